// Round 3
// baseline (1426.316 us; speedup 1.0000x reference)
//
#include <hip/hip_runtime.h>
#include <hip/hip_cooperative_groups.h>
#include <math.h>

namespace cg = cooperative_groups;

#define N_NODES 2000
#define NA 16
#define NOBS 64
#define NH 128
#define NE 16000
#define NITERS 8

// ---------------- workspace layout (float offsets) ----------------
#define WS_MSG       0                       // 2E*16 = 512000 floats (single buffer)
#define WS_SBUF      512000                  // 9 x 32000 = 288000 (S[0] stays zero)
#define WS_Q         800000                  // 8
#define WS_ZERO_CNT  800008                  // everything above zeroed in setup
#define WS_AIDX      800016                  // int[8*2000] = 16000
#define WS_W         816016                  // int[16000]
#define WS_PT        832016                  // pT 4,096,000 floats; owner map (4,000,000 ints) aliases
#define WS_WB        4928016                 // transposed weights base
#define WS_UW0T      (WS_WB + 0)             // 128x256
#define WS_UW1T      (WS_WB + 32768)         // 256x256
#define WS_UW2T      (WS_WB + 98304)         // 256x16
#define WS_PW0T      (WS_WB + 102400)        // 256x128
#define WS_PW1T      (WS_WB + 135168)        // 128x256
#define WS_PW2T      (WS_WB + 167936)        // 256x256
#define WS_PW3T      (WS_WB + 233472)        // 256x16
#define WS_PW4T      (WS_WB + 237568)        // 16x256
// end: 5,169,680 floats (~20.7 MB)

// ---------------- setup: zero state, init owner map, transpose weights -------
__global__ __launch_bounds__(256) void setup_kernel(
    float* __restrict__ ws,
    const float* __restrict__ uW0, const float* __restrict__ uW1,
    const float* __restrict__ uW2, const float* __restrict__ pW0,
    const float* __restrict__ pW1, const float* __restrict__ pW2,
    const float* __restrict__ pW3, const float* __restrict__ pW4)
{
    const int total = WS_ZERO_CNT + 4000000 + 241664;
    int* owner = (int*)(ws + WS_PT);
    for (int idx = blockIdx.x * 256 + threadIdx.x; idx < total;
         idx += gridDim.x * 256) {
        if (idx < WS_ZERO_CNT) {
            ws[idx] = 0.f;
        } else if (idx < WS_ZERO_CNT + 4000000) {
            owner[idx - WS_ZERO_CNT] = -1;
        } else {
            int t = idx - (WS_ZERO_CNT + 4000000);
            const float* src; float* dst; int K, O;
            if      (t < 32768)              { src = uW0; dst = ws + WS_UW0T; K = 128; O = 256; }
            else if (t < 98304)  { t -= 32768;  src = uW1; dst = ws + WS_UW1T; K = 256; O = 256; }
            else if (t < 102400) { t -= 98304;  src = uW2; dst = ws + WS_UW2T; K = 256; O = 16;  }
            else if (t < 135168) { t -= 102400; src = pW0; dst = ws + WS_PW0T; K = 256; O = 128; }
            else if (t < 167936) { t -= 135168; src = pW1; dst = ws + WS_PW1T; K = 128; O = 256; }
            else if (t < 233472) { t -= 167936; src = pW2; dst = ws + WS_PW2T; K = 256; O = 256; }
            else if (t < 237568) { t -= 233472; src = pW3; dst = ws + WS_PW3T; K = 256; O = 16;  }
            else                 { t -= 237568; src = pW4; dst = ws + WS_PW4T; K = 16;  O = 256; }
            int k = t / O, o = t % O;
            dst[t] = src[o * K + k];
            (void)K;
        }
    }
}

// ---------------- dedup: claim representative per (i,j) pair ----------------
__global__ __launch_bounds__(256) void claim_kernel(
    const int* __restrict__ edges, int* __restrict__ owner)
{
    int e = blockIdx.x * 256 + threadIdx.x;
    if (e < NE) {
        int i = edges[2 * e], j = edges[2 * e + 1];
        atomicMax(&owner[i * N_NODES + j], e);
    }
}

__global__ __launch_bounds__(256) void resolve_kernel(
    const int* __restrict__ edges, const int* __restrict__ owner,
    int* __restrict__ wflag)
{
    int e = blockIdx.x * 256 + threadIdx.x;
    if (e < NE) {
        int i = edges[2 * e], j = edges[2 * e + 1];
        wflag[e] = (owner[i * N_NODES + j] == e) ? 1 : 0;
    }
}

// ---------------- GRU encoder: h = GRUCell(concat(x,pa), state) -------------
__global__ __launch_bounds__(256) void gru_kernel(
    const float* __restrict__ x, const float* __restrict__ pa,
    const float* __restrict__ st, const float* __restrict__ wih,
    const float* __restrict__ whh, const float* __restrict__ bih,
    const float* __restrict__ bhh, float* __restrict__ h_out)
{
    __shared__ float enc[8][80];
    __shared__ float hp[8][128];
    __shared__ float gi[8][384];
    __shared__ float gh[8][384];
    const int tid = threadIdx.x;
    const int n0 = blockIdx.x * 8;

    for (int idx = tid; idx < 8 * 80; idx += 256) {
        int r = idx / 80, c = idx % 80;
        enc[r][c] = (c < 64) ? x[(n0 + r) * 64 + c] : pa[(n0 + r) * 16 + (c - 64)];
    }
    for (int idx = tid; idx < 8 * 128; idx += 256) {
        int r = idx >> 7, c = idx & 127;
        hp[r][c] = st[(n0 + r) * 128 + c];
    }
    __syncthreads();

    for (int idx = tid; idx < 8 * 384; idx += 256) {
        int g = idx % 384, r = idx / 384;
        float s1 = bih[g];
        const float* wr = wih + g * 80;
        #pragma unroll 8
        for (int k = 0; k < 80; ++k) s1 = fmaf(enc[r][k], wr[k], s1);
        gi[r][g] = s1;
        float s2 = bhh[g];
        const float* wr2 = whh + g * 128;
        #pragma unroll 8
        for (int k = 0; k < 128; ++k) s2 = fmaf(hp[r][k], wr2[k], s2);
        gh[r][g] = s2;
    }
    __syncthreads();

    for (int idx = tid; idx < 8 * 128; idx += 256) {
        int r = idx >> 7, c = idx & 127;
        float rr = 1.f / (1.f + expf(-(gi[r][c] + gh[r][c])));
        float zz = 1.f / (1.f + expf(-(gi[r][128 + c] + gh[r][128 + c])));
        float nn = tanhf(gi[r][256 + c] + rr * gh[r][256 + c]);
        h_out[(n0 + r) * 128 + c] = (1.f - zz) * nn + zz * hp[r][c];
    }
}

// ---------------- u MLP: 128 -> 256 -> 256 -> 16, /N ----------------
__global__ __launch_bounds__(256) void umlp_kernel(
    const float* __restrict__ h, const float* __restrict__ w0t,
    const float* __restrict__ b0, const float* __restrict__ w1t,
    const float* __restrict__ b1, const float* __restrict__ w2t,
    const float* __restrict__ b2, float* __restrict__ u_out)
{
    __shared__ float A[16][128];
    __shared__ float B[16][256];
    const int tid = threadIdx.x;
    const int n0 = blockIdx.x * 16;

    for (int idx = tid; idx < 16 * 128; idx += 256) {
        int r = idx >> 7, c = idx & 127;
        A[r][c] = h[(n0 + r) * 128 + c];
    }
    __syncthreads();
    // L0: 128->256 relu, A->B
    {
        int o = tid;
        float acc[16];
        #pragma unroll
        for (int r = 0; r < 16; ++r) acc[r] = b0[o];
        for (int k4 = 0; k4 < 32; ++k4) {
            float w0v = w0t[(4 * k4 + 0) * 256 + o];
            float w1v = w0t[(4 * k4 + 1) * 256 + o];
            float w2v = w0t[(4 * k4 + 2) * 256 + o];
            float w3v = w0t[(4 * k4 + 3) * 256 + o];
            #pragma unroll
            for (int r = 0; r < 16; ++r) {
                const float4 av = *(const float4*)&A[r][4 * k4];
                acc[r] = fmaf(av.x, w0v, fmaf(av.y, w1v, fmaf(av.z, w2v, fmaf(av.w, w3v, acc[r]))));
            }
        }
        #pragma unroll
        for (int r = 0; r < 16; ++r) B[r][o] = fmaxf(acc[r], 0.f);
    }
    __syncthreads();
    // L1: 256->256 relu, B->B (register staged)
    {
        int o = tid;
        float acc[16];
        #pragma unroll
        for (int r = 0; r < 16; ++r) acc[r] = b1[o];
        for (int k4 = 0; k4 < 64; ++k4) {
            float w0v = w1t[(4 * k4 + 0) * 256 + o];
            float w1v = w1t[(4 * k4 + 1) * 256 + o];
            float w2v = w1t[(4 * k4 + 2) * 256 + o];
            float w3v = w1t[(4 * k4 + 3) * 256 + o];
            #pragma unroll
            for (int r = 0; r < 16; ++r) {
                const float4 av = *(const float4*)&B[r][4 * k4];
                acc[r] = fmaf(av.x, w0v, fmaf(av.y, w1v, fmaf(av.z, w2v, fmaf(av.w, w3v, acc[r]))));
            }
        }
        __syncthreads();
        #pragma unroll
        for (int r = 0; r < 16; ++r) B[r][o] = fmaxf(acc[r], 0.f);
    }
    __syncthreads();
    // L2: 256->16, /N, no relu
    {
        int r = tid >> 4, o = tid & 15;
        float acc = b2[o];
        for (int k4 = 0; k4 < 64; ++k4) {
            const float4 av = *(const float4*)&B[r][4 * k4];
            acc = fmaf(av.x, w2t[(4 * k4 + 0) * 16 + o],
                  fmaf(av.y, w2t[(4 * k4 + 1) * 16 + o],
                  fmaf(av.z, w2t[(4 * k4 + 2) * 16 + o],
                  fmaf(av.w, w2t[(4 * k4 + 3) * 16 + o], acc))));
        }
        u_out[(n0 + r) * 16 + o] = acc * (1.f / N_NODES);
    }
}

// ---------------- p MLP: 256->128->256->256->16->256, avg dirs, /E ----------
// wave = row-group of 8 rows; thread = (rg, ct) with C output cols per thread.
__global__ __launch_bounds__(256, 3) void pmlp_kernel(
    const float* __restrict__ h, const int* __restrict__ edges,
    const float* __restrict__ w0t, const float* __restrict__ b0,
    const float* __restrict__ w1t, const float* __restrict__ b1,
    const float* __restrict__ w2t, const float* __restrict__ b2,
    const float* __restrict__ w3t, const float* __restrict__ b3,
    const float* __restrict__ w4t, const float* __restrict__ b4,
    float* __restrict__ p_out, float* __restrict__ pT)
{
    __shared__ float A[32][256];   // 32 KB
    __shared__ float B[32][128];   // 16 KB
    __shared__ float C16[32][16];  // 2 KB
    __shared__ int fi[32], se[32];
    const int tid = threadIdx.x;
    const int e0 = blockIdx.x * 16;
    const int rg = tid >> 6;       // wave id = row group
    const int ct = tid & 63;
    const int r0 = rg * 8;

    if (tid < 16) {
        int i = edges[2 * (e0 + tid)], j = edges[2 * (e0 + tid) + 1];
        fi[2 * tid] = i;     se[2 * tid] = j;       // row 2s  = [h_i | h_j]
        fi[2 * tid + 1] = j; se[2 * tid + 1] = i;   // row 2s+1 = [h_j | h_i]
    }
    __syncthreads();
    {
        int c = tid, cl = c & 127;
        for (int r = 0; r < 32; ++r) {
            int node = (c < 128) ? fi[r] : se[r];
            A[r][c] = h[node * 128 + cl];
        }
    }
    __syncthreads();
    // L0: 256->128 relu, A->B.  C=2 cols/thread (float2 weights), prefetched.
    {
        const float2* wp = (const float2*)w0t + ct;   // w0t[k*128 + 2ct]
        float2 cw[4], nw[4];
        #pragma unroll
        for (int c = 0; c < 4; ++c) cw[c] = wp[c * 64];
        float2 bb = ((const float2*)b0)[ct];
        float a0[8], a1[8];
        #pragma unroll
        for (int r = 0; r < 8; ++r) { a0[r] = bb.x; a1[r] = bb.y; }
        for (int k4 = 0; k4 < 64; ++k4) {
            if (k4 < 63) {
                #pragma unroll
                for (int c = 0; c < 4; ++c) nw[c] = wp[(4 * k4 + 4 + c) * 64];
            }
            #pragma unroll
            for (int r = 0; r < 8; ++r) {
                const float4 av = *(const float4*)&A[r0 + r][4 * k4];
                a0[r] = fmaf(av.x, cw[0].x, fmaf(av.y, cw[1].x, fmaf(av.z, cw[2].x, fmaf(av.w, cw[3].x, a0[r]))));
                a1[r] = fmaf(av.x, cw[0].y, fmaf(av.y, cw[1].y, fmaf(av.z, cw[2].y, fmaf(av.w, cw[3].y, a1[r]))));
            }
            #pragma unroll
            for (int c = 0; c < 4; ++c) cw[c] = nw[c];
        }
        #pragma unroll
        for (int r = 0; r < 8; ++r) {
            B[r0 + r][2 * ct]     = fmaxf(a0[r], 0.f);
            B[r0 + r][2 * ct + 1] = fmaxf(a1[r], 0.f);
        }
    }
    __syncthreads();
    // L1: 128->256 relu, B->A.  C=4 cols/thread (float4 weights), prefetched.
    {
        const float4* wp = (const float4*)w1t + ct;   // w1t[k*256 + 4ct]
        float4 cw[4], nw[4];
        #pragma unroll
        for (int c = 0; c < 4; ++c) cw[c] = wp[c * 64];
        float4 bb = ((const float4*)b1)[ct];
        float acc[8][4];
        #pragma unroll
        for (int r = 0; r < 8; ++r) {
            acc[r][0] = bb.x; acc[r][1] = bb.y; acc[r][2] = bb.z; acc[r][3] = bb.w;
        }
        for (int k4 = 0; k4 < 32; ++k4) {
            if (k4 < 31) {
                #pragma unroll
                for (int c = 0; c < 4; ++c) nw[c] = wp[(4 * k4 + 4 + c) * 64];
            }
            #pragma unroll
            for (int r = 0; r < 8; ++r) {
                const float4 av = *(const float4*)&B[r0 + r][4 * k4];
                acc[r][0] = fmaf(av.x, cw[0].x, fmaf(av.y, cw[1].x, fmaf(av.z, cw[2].x, fmaf(av.w, cw[3].x, acc[r][0]))));
                acc[r][1] = fmaf(av.x, cw[0].y, fmaf(av.y, cw[1].y, fmaf(av.z, cw[2].y, fmaf(av.w, cw[3].y, acc[r][1]))));
                acc[r][2] = fmaf(av.x, cw[0].z, fmaf(av.y, cw[1].z, fmaf(av.z, cw[2].z, fmaf(av.w, cw[3].z, acc[r][2]))));
                acc[r][3] = fmaf(av.x, cw[0].w, fmaf(av.y, cw[1].w, fmaf(av.z, cw[2].w, fmaf(av.w, cw[3].w, acc[r][3]))));
            }
            #pragma unroll
            for (int c = 0; c < 4; ++c) cw[c] = nw[c];
        }
        #pragma unroll
        for (int r = 0; r < 8; ++r) {
            float4 v = make_float4(fmaxf(acc[r][0], 0.f), fmaxf(acc[r][1], 0.f),
                                   fmaxf(acc[r][2], 0.f), fmaxf(acc[r][3], 0.f));
            *(float4*)&A[r0 + r][4 * ct] = v;
        }
    }
    __syncthreads();
    // L2: 256->256 relu, A->A (register staged).  C=4, prefetched.
    {
        const float4* wp = (const float4*)w2t + ct;
        float4 cw[4], nw[4];
        #pragma unroll
        for (int c = 0; c < 4; ++c) cw[c] = wp[c * 64];
        float4 bb = ((const float4*)b2)[ct];
        float acc[8][4];
        #pragma unroll
        for (int r = 0; r < 8; ++r) {
            acc[r][0] = bb.x; acc[r][1] = bb.y; acc[r][2] = bb.z; acc[r][3] = bb.w;
        }
        for (int k4 = 0; k4 < 64; ++k4) {
            if (k4 < 63) {
                #pragma unroll
                for (int c = 0; c < 4; ++c) nw[c] = wp[(4 * k4 + 4 + c) * 64];
            }
            #pragma unroll
            for (int r = 0; r < 8; ++r) {
                const float4 av = *(const float4*)&A[r0 + r][4 * k4];
                acc[r][0] = fmaf(av.x, cw[0].x, fmaf(av.y, cw[1].x, fmaf(av.z, cw[2].x, fmaf(av.w, cw[3].x, acc[r][0]))));
                acc[r][1] = fmaf(av.x, cw[0].y, fmaf(av.y, cw[1].y, fmaf(av.z, cw[2].y, fmaf(av.w, cw[3].y, acc[r][1]))));
                acc[r][2] = fmaf(av.x, cw[0].z, fmaf(av.y, cw[1].z, fmaf(av.z, cw[2].z, fmaf(av.w, cw[3].z, acc[r][2]))));
                acc[r][3] = fmaf(av.x, cw[0].w, fmaf(av.y, cw[1].w, fmaf(av.z, cw[2].w, fmaf(av.w, cw[3].w, acc[r][3]))));
            }
            #pragma unroll
            for (int c = 0; c < 4; ++c) cw[c] = nw[c];
        }
        __syncthreads();
        #pragma unroll
        for (int r = 0; r < 8; ++r) {
            float4 v = make_float4(fmaxf(acc[r][0], 0.f), fmaxf(acc[r][1], 0.f),
                                   fmaxf(acc[r][2], 0.f), fmaxf(acc[r][3], 0.f));
            *(float4*)&A[r0 + r][4 * ct] = v;
        }
    }
    __syncthreads();
    // L3: 256->16 relu, A->C16   (512 tasks)
    for (int idx = tid; idx < 512; idx += 256) {
        int r = idx >> 4, o = idx & 15;
        float acc = b3[o];
        for (int k4 = 0; k4 < 64; ++k4) {
            const float4 av = *(const float4*)&A[r][4 * k4];
            acc = fmaf(av.x, w3t[(4 * k4 + 0) * 16 + o],
                  fmaf(av.y, w3t[(4 * k4 + 1) * 16 + o],
                  fmaf(av.z, w3t[(4 * k4 + 2) * 16 + o],
                  fmaf(av.w, w3t[(4 * k4 + 3) * 16 + o], acc))));
        }
        C16[r][o] = fmaxf(acc, 0.f);
    }
    __syncthreads();
    // L4: 16->256 (no relu), combine dirs, /E ; write p and pT
    {
        int o = tid;
        int ai = o >> 4, aj = o & 15;
        float acc[32];
        #pragma unroll
        for (int r = 0; r < 32; ++r) acc[r] = b4[o];
        #pragma unroll
        for (int k4 = 0; k4 < 4; ++k4) {
            float w0v = w4t[(4 * k4 + 0) * 256 + o];
            float w1v = w4t[(4 * k4 + 1) * 256 + o];
            float w2v = w4t[(4 * k4 + 2) * 256 + o];
            float w3v = w4t[(4 * k4 + 3) * 256 + o];
            #pragma unroll
            for (int r = 0; r < 32; ++r) {
                const float4 av = *(const float4*)&C16[r][4 * k4];
                acc[r] = fmaf(av.x, w0v, fmaf(av.y, w1v, fmaf(av.z, w2v, fmaf(av.w, w3v, acc[r]))));
            }
        }
        #pragma unroll
        for (int s = 0; s < 16; ++s) {
            float v = 0.5f * (acc[2 * s] + acc[2 * s + 1]) * (1.f / NE);
            p_out[(e0 + s) * 256 + o] = v;
            pT[(e0 + s) * 256 + aj * 16 + ai] = v;   // pT[e][aj][ai]
        }
    }
}

// ---------------- fused message passing (cooperative) -----------------------
// 8 edge phases with grid.sync between; S kept per-iteration (S[t+1] written
// by iter t, S[0] all-zero). Node/argmax/q phase runs ONCE over all 8 iters
// (it never feeds the recursion), then final selection writes a/q.
// Per-edge invariants (i, j, wflag, p-column, vmax, u_i, u_j) hoisted.
__global__ __launch_bounds__(256, 4) void mp_coop_kernel(
    const float* __restrict__ u, float* __restrict__ Sbuf,
    float* __restrict__ msg, const float* __restrict__ pT,
    const float* __restrict__ p, const int* __restrict__ edges,
    const int* __restrict__ wflag, int* __restrict__ aidx,
    float* __restrict__ q, float* __restrict__ a_out,
    float* __restrict__ q_out)
{
    cg::grid_group grid = cg::this_grid();
    const int gid = blockIdx.x * 256 + threadIdx.x;
    const int e = gid >> 4;
    const int L = gid & 15;

    // hoisted per-edge invariants
    int i = 0, j = 0, wf = 0;
    float u_i = 0.f, u_j = 0.f, vmax = 0.f;
    float pv[16];
    if (e < NE) {
        i = edges[2 * e]; j = edges[2 * e + 1]; wf = wflag[e];
        u_i = u[i * 16 + L]; u_j = u[j * 16 + L];
        const float4* pt = (const float4*)(pT + e * 256 + L * 16);  // pT[e][L][*] = p[e][*][L]
        const float4 q0 = pt[0], q1 = pt[1], q2 = pt[2], q3 = pt[3];
        pv[0]=q0.x; pv[1]=q0.y; pv[2]=q0.z; pv[3]=q0.w;
        pv[4]=q1.x; pv[5]=q1.y; pv[6]=q1.z; pv[7]=q1.w;
        pv[8]=q2.x; pv[9]=q2.y; pv[10]=q2.z; pv[11]=q2.w;
        pv[12]=q3.x; pv[13]=q3.y; pv[14]=q3.z; pv[15]=q3.w;
        vmax = pv[0];
        #pragma unroll
        for (int a = 1; a < 16; ++a) vmax = fmaxf(vmax, pv[a]);
    }

    for (int t = 0; t < NITERS; ++t) {
        if (e < NE) {
            const float* So = Sbuf + t * 32000;
            float* Sn = Sbuf + (t + 1) * 32000;
            const float mold_ij = msg[(NE + e) * 16 + L];   // into i
            const float mold_ji = msg[e * 16 + L];          // into j
            const float bi = u_i + So[i * 16 + L] - mold_ij;
            const float bj = u_j + So[j * 16 + L] - mold_ji;
            float mj = -INFINITY;
            #pragma unroll
            for (int a = 0; a < 16; ++a) {
                float bia = __shfl(bi, a, 16);
                mj = fmaxf(mj, pv[a] + bia);
            }
            float mi = vmax + bj;
            float sj = mj, si = mi;
            #pragma unroll
            for (int off = 1; off < 16; off <<= 1) {
                sj += __shfl_xor(sj, off, 16);
                si += __shfl_xor(si, off, 16);
            }
            mj -= sj * (1.f / 16.f);
            mi -= si * (1.f / 16.f);
            msg[e * 16 + L] = mj;
            msg[(NE + e) * 16 + L] = mi;
            if (wf) {  // only the representative of a duplicate pair feeds S
                atomicAdd(&Sn[j * 16 + L], mj);
                atomicAdd(&Sn[i * 16 + L], mi);
            }
        }
        grid.sync();
    }

    // node phase, all 8 iterations at once. 18048 = 282*64 padded tasks/iter
    // so each wave's lanes share one t (wave-reduce + 1 atomic/wave).
    const int TPER = 18048;
    for (int task = gid; task < NITERS * TPER; task += gridDim.x * 256) {
        const int t = task / TPER;
        const int r = task - t * TPER;
        const float* Sn = Sbuf + (t + 1) * 32000;
        float partial = 0.f;
        if (r < N_NODES) {
            int n = r;
            float bv = u[n * 16] + Sn[n * 16];
            int best = 0;
            #pragma unroll
            for (int a = 1; a < 16; ++a) {
                float v = u[n * 16 + a] + Sn[n * 16 + a];
                if (v > bv) { bv = v; best = a; }
            }
            aidx[t * N_NODES + n] = best;
            partial = u[n * 16 + best];
        } else if (r < N_NODES + NE) {
            int ee = r - N_NODES;
            int ii = edges[2 * ee], jj = edges[2 * ee + 1];
            float bvi = u[ii * 16] + Sn[ii * 16]; int ai = 0;
            #pragma unroll
            for (int a = 1; a < 16; ++a) {
                float v = u[ii * 16 + a] + Sn[ii * 16 + a];
                if (v > bvi) { bvi = v; ai = a; }
            }
            float bvj = u[jj * 16] + Sn[jj * 16]; int aj = 0;
            #pragma unroll
            for (int a = 1; a < 16; ++a) {
                float v = u[jj * 16 + a] + Sn[jj * 16 + a];
                if (v > bvj) { bvj = v; aj = a; }
            }
            partial = p[ee * 256 + ai * 16 + aj];
        }
        #pragma unroll
        for (int off = 1; off < 64; off <<= 1) partial += __shfl_xor(partial, off, 64);
        if ((threadIdx.x & 63) == 0) atomicAdd(&q[t], partial);
    }
    grid.sync();

    // final: running strict-> max over iters, one-hot a
    for (int id = gid; id < N_NODES * 16; id += gridDim.x * 256) {
        float cur = 0.f; int best_t = -1;
        #pragma unroll
        for (int t = 0; t < NITERS; ++t) {
            float qv = q[t];
            if (qv > cur) { cur = qv; best_t = t; }
        }
        int n = id >> 4, c = id & 15;
        float val = 0.f;
        if (best_t >= 0 && aidx[best_t * N_NODES + n] == c) val = 1.f;
        a_out[id] = val;
        if (id == 0) q_out[0] = cur;
    }
}

extern "C" void kernel_launch(void* const* d_in, const int* in_sizes, int n_in,
                              void* d_out, int out_size, void* d_ws, size_t ws_size,
                              hipStream_t stream)
{
    (void)in_sizes; (void)n_in; (void)out_size; (void)ws_size;
    const float* x    = (const float*)d_in[0];
    const float* pa   = (const float*)d_in[1];
    const float* st   = (const float*)d_in[2];
    const int*   edges= (const int*)d_in[3];
    const float* gwih = (const float*)d_in[4];
    const float* gwhh = (const float*)d_in[5];
    const float* gbih = (const float*)d_in[6];
    const float* gbhh = (const float*)d_in[7];
    const float* uW0 = (const float*)d_in[8];  const float* ub0 = (const float*)d_in[9];
    const float* uW1 = (const float*)d_in[10]; const float* ub1 = (const float*)d_in[11];
    const float* uW2 = (const float*)d_in[12]; const float* ub2 = (const float*)d_in[13];
    const float* pW0 = (const float*)d_in[14]; const float* pb0 = (const float*)d_in[15];
    const float* pW1 = (const float*)d_in[16]; const float* pb1 = (const float*)d_in[17];
    const float* pW2 = (const float*)d_in[18]; const float* pb2 = (const float*)d_in[19];
    const float* pW3 = (const float*)d_in[20]; const float* pb3 = (const float*)d_in[21];
    const float* pW4 = (const float*)d_in[22]; const float* pb4 = (const float*)d_in[23];

    float* out   = (float*)d_out;
    float* a_out = out;                 // 32000
    float* q_out = out + 32000;         // 1
    float* u_out = out + 32001;         // 32000
    float* p_out = out + 64001;         // 4,096,000
    float* h_out = out + 4160001;       // 256,000 (state_out)

    float* ws   = (float*)d_ws;
    float* msg  = ws + WS_MSG;
    float* Sbuf = ws + WS_SBUF;
    float* q    = ws + WS_Q;
    int*   aidx = (int*)(ws + WS_AIDX);
    int*   wfl  = (int*)(ws + WS_W);
    float* pT   = ws + WS_PT;
    int*   owner= (int*)(ws + WS_PT);   // aliases pT; dead before pmlp runs

    setup_kernel<<<2048, 256, 0, stream>>>(ws, uW0, uW1, uW2, pW0, pW1, pW2, pW3, pW4);
    claim_kernel<<<(NE + 255) / 256, 256, 0, stream>>>(edges, owner);
    resolve_kernel<<<(NE + 255) / 256, 256, 0, stream>>>(edges, owner, wfl);
    gru_kernel<<<N_NODES / 8, 256, 0, stream>>>(x, pa, st, gwih, gwhh, gbih, gbhh, h_out);
    umlp_kernel<<<N_NODES / 16, 256, 0, stream>>>(h_out, ws + WS_UW0T, ub0,
                                                  ws + WS_UW1T, ub1, ws + WS_UW2T, ub2, u_out);
    pmlp_kernel<<<NE / 16, 256, 0, stream>>>(h_out, edges,
                                             ws + WS_PW0T, pb0, ws + WS_PW1T, pb1,
                                             ws + WS_PW2T, pb2, ws + WS_PW3T, pb3,
                                             ws + WS_PW4T, pb4, p_out, pT);
    {
        void* args[] = {
            (void*)&u_out, (void*)&Sbuf, (void*)&msg, (void*)&pT, (void*)&p_out,
            (void*)&edges, (void*)&wfl, (void*)&aidx, (void*)&q,
            (void*)&a_out, (void*)&q_out
        };
        hipLaunchCooperativeKernel((const void*)mp_coop_kernel,
                                   dim3(1024), dim3(256), args, 0, stream);
    }
}

// Round 4
// 443.478 us; speedup vs baseline: 3.2162x; 3.2162x over previous
//
#include <hip/hip_runtime.h>
#include <math.h>

#define N_NODES 2000
#define NA 16
#define NOBS 64
#define NH 128
#define NE 16000
#define NITERS 8

// ---------------- workspace layout (float offsets) ----------------
#define WS_MSG       0                       // 2E*16 = 512000 floats (single buffer)
#define WS_SBUF      512000                  // 9 x 32000 = 288000 (S[0] stays zero)
#define WS_Q         800000                  // 8
#define WS_ZERO_CNT  800008                  // everything above zeroed in setup
#define WS_AIDX      800016                  // int[8*2000] = 16000
#define WS_W         816016                  // int[16000]
#define WS_PT        832016                  // pT 4,096,000 floats; owner map (4,000,000 ints) aliases
#define WS_GIT       (WS_PT + 4000000)       // wihT 80x384 = 30720 (spare of PT region; dead after gru)
#define WS_GHT       (WS_GIT + 30720)        // whhT 128x384 = 49152 (end 4,911,888 < WS_WB)
#define WS_WB        4928016                 // transposed weights base
#define WS_UW0T      (WS_WB + 0)             // 128x256
#define WS_UW1T      (WS_WB + 32768)         // 256x256
#define WS_UW2T      (WS_WB + 98304)         // 256x16
#define WS_PW0T      (WS_WB + 102400)        // 256x128
#define WS_PW1T      (WS_WB + 135168)        // 128x256
#define WS_PW2T      (WS_WB + 167936)        // 256x256
#define WS_PW3T      (WS_WB + 233472)        // 256x16
#define WS_PW4T      (WS_WB + 237568)        // 16x256
// end: 5,169,680 floats (~20.7 MB) — same footprint as round 3

// ---------------- setup: zero state, init owner map, transpose weights -------
__global__ __launch_bounds__(256) void setup_kernel(
    float* __restrict__ ws,
    const float* __restrict__ uW0, const float* __restrict__ uW1,
    const float* __restrict__ uW2, const float* __restrict__ pW0,
    const float* __restrict__ pW1, const float* __restrict__ pW2,
    const float* __restrict__ pW3, const float* __restrict__ pW4,
    const float* __restrict__ gwih, const float* __restrict__ gwhh)
{
    const int total = WS_ZERO_CNT + 4000000 + 321536;
    int* owner = (int*)(ws + WS_PT);
    for (int idx = blockIdx.x * 256 + threadIdx.x; idx < total;
         idx += gridDim.x * 256) {
        if (idx < WS_ZERO_CNT) {
            ws[idx] = 0.f;
        } else if (idx < WS_ZERO_CNT + 4000000) {
            owner[idx - WS_ZERO_CNT] = -1;
        } else {
            int t = idx - (WS_ZERO_CNT + 4000000);
            const float* src; float* dst; int K, O;
            if      (t < 32768)              { src = uW0;  dst = ws + WS_UW0T; K = 128; O = 256; }
            else if (t < 98304)  { t -= 32768;  src = uW1;  dst = ws + WS_UW1T; K = 256; O = 256; }
            else if (t < 102400) { t -= 98304;  src = uW2;  dst = ws + WS_UW2T; K = 256; O = 16;  }
            else if (t < 135168) { t -= 102400; src = pW0;  dst = ws + WS_PW0T; K = 256; O = 128; }
            else if (t < 167936) { t -= 135168; src = pW1;  dst = ws + WS_PW1T; K = 128; O = 256; }
            else if (t < 233472) { t -= 167936; src = pW2;  dst = ws + WS_PW2T; K = 256; O = 256; }
            else if (t < 237568) { t -= 233472; src = pW3;  dst = ws + WS_PW3T; K = 256; O = 16;  }
            else if (t < 241664) { t -= 237568; src = pW4;  dst = ws + WS_PW4T; K = 16;  O = 256; }
            else if (t < 272384) { t -= 241664; src = gwih; dst = ws + WS_GIT;  K = 80;  O = 384; }
            else                 { t -= 272384; src = gwhh; dst = ws + WS_GHT;  K = 128; O = 384; }
            int k = t / O, o = t % O;
            dst[t] = src[o * K + k];
            (void)K;
        }
    }
}

// ---------------- dedup: claim representative per (i,j) pair ----------------
__global__ __launch_bounds__(256) void claim_kernel(
    const int* __restrict__ edges, int* __restrict__ owner)
{
    int e = blockIdx.x * 256 + threadIdx.x;
    if (e < NE) {
        int i = edges[2 * e], j = edges[2 * e + 1];
        atomicMax(&owner[i * N_NODES + j], e);
    }
}

__global__ __launch_bounds__(256) void resolve_kernel(
    const int* __restrict__ edges, const int* __restrict__ owner,
    int* __restrict__ wflag)
{
    int e = blockIdx.x * 256 + threadIdx.x;
    if (e < NE) {
        int i = edges[2 * e], j = edges[2 * e + 1];
        wflag[e] = (owner[i * N_NODES + j] == e) ? 1 : 0;
    }
}

// ---------------- GRU encoder: h = GRUCell(concat(x,pa), state) -------------
// weights pre-transposed (wihT[k][g], whhT[k][g]) so loads are lane-coalesced.
__global__ __launch_bounds__(256) void gru_kernel(
    const float* __restrict__ x, const float* __restrict__ pa,
    const float* __restrict__ st, const float* __restrict__ wihT,
    const float* __restrict__ whhT, const float* __restrict__ bih,
    const float* __restrict__ bhh, float* __restrict__ h_out)
{
    __shared__ float enc[8][80];
    __shared__ float hp[8][128];
    __shared__ float gi[8][384];
    __shared__ float gh[8][384];
    const int tid = threadIdx.x;
    const int n0 = blockIdx.x * 8;

    for (int idx = tid; idx < 8 * 80; idx += 256) {
        int r = idx / 80, c = idx % 80;
        enc[r][c] = (c < 64) ? x[(n0 + r) * 64 + c] : pa[(n0 + r) * 16 + (c - 64)];
    }
    for (int idx = tid; idx < 8 * 128; idx += 256) {
        int r = idx >> 7, c = idx & 127;
        hp[r][c] = st[(n0 + r) * 128 + c];
    }
    __syncthreads();

    for (int idx = tid; idx < 8 * 384; idx += 256) {
        int g = idx % 384, r = idx / 384;
        float s1 = bih[g];
        #pragma unroll 8
        for (int k = 0; k < 80; ++k) s1 = fmaf(enc[r][k], wihT[k * 384 + g], s1);
        gi[r][g] = s1;
        float s2 = bhh[g];
        #pragma unroll 8
        for (int k = 0; k < 128; ++k) s2 = fmaf(hp[r][k], whhT[k * 384 + g], s2);
        gh[r][g] = s2;
    }
    __syncthreads();

    for (int idx = tid; idx < 8 * 128; idx += 256) {
        int r = idx >> 7, c = idx & 127;
        float rr = 1.f / (1.f + expf(-(gi[r][c] + gh[r][c])));
        float zz = 1.f / (1.f + expf(-(gi[r][128 + c] + gh[r][128 + c])));
        float nn = tanhf(gi[r][256 + c] + rr * gh[r][256 + c]);
        h_out[(n0 + r) * 128 + c] = (1.f - zz) * nn + zz * hp[r][c];
    }
}

// ---------------- u MLP: 128 -> 256 -> 256 -> 16, /N ----------------
__global__ __launch_bounds__(256) void umlp_kernel(
    const float* __restrict__ h, const float* __restrict__ w0t,
    const float* __restrict__ b0, const float* __restrict__ w1t,
    const float* __restrict__ b1, const float* __restrict__ w2t,
    const float* __restrict__ b2, float* __restrict__ u_out)
{
    __shared__ float A[16][128];
    __shared__ float B[16][256];
    const int tid = threadIdx.x;
    const int n0 = blockIdx.x * 16;

    for (int idx = tid; idx < 16 * 128; idx += 256) {
        int r = idx >> 7, c = idx & 127;
        A[r][c] = h[(n0 + r) * 128 + c];
    }
    __syncthreads();
    // L0: 128->256 relu, A->B
    {
        int o = tid;
        float acc[16];
        #pragma unroll
        for (int r = 0; r < 16; ++r) acc[r] = b0[o];
        for (int k4 = 0; k4 < 32; ++k4) {
            float w0v = w0t[(4 * k4 + 0) * 256 + o];
            float w1v = w0t[(4 * k4 + 1) * 256 + o];
            float w2v = w0t[(4 * k4 + 2) * 256 + o];
            float w3v = w0t[(4 * k4 + 3) * 256 + o];
            #pragma unroll
            for (int r = 0; r < 16; ++r) {
                const float4 av = *(const float4*)&A[r][4 * k4];
                acc[r] = fmaf(av.x, w0v, fmaf(av.y, w1v, fmaf(av.z, w2v, fmaf(av.w, w3v, acc[r]))));
            }
        }
        #pragma unroll
        for (int r = 0; r < 16; ++r) B[r][o] = fmaxf(acc[r], 0.f);
    }
    __syncthreads();
    // L1: 256->256 relu, B->B (register staged)
    {
        int o = tid;
        float acc[16];
        #pragma unroll
        for (int r = 0; r < 16; ++r) acc[r] = b1[o];
        for (int k4 = 0; k4 < 64; ++k4) {
            float w0v = w1t[(4 * k4 + 0) * 256 + o];
            float w1v = w1t[(4 * k4 + 1) * 256 + o];
            float w2v = w1t[(4 * k4 + 2) * 256 + o];
            float w3v = w1t[(4 * k4 + 3) * 256 + o];
            #pragma unroll
            for (int r = 0; r < 16; ++r) {
                const float4 av = *(const float4*)&B[r][4 * k4];
                acc[r] = fmaf(av.x, w0v, fmaf(av.y, w1v, fmaf(av.z, w2v, fmaf(av.w, w3v, acc[r]))));
            }
        }
        __syncthreads();
        #pragma unroll
        for (int r = 0; r < 16; ++r) B[r][o] = fmaxf(acc[r], 0.f);
    }
    __syncthreads();
    // L2: 256->16, /N, no relu
    {
        int r = tid >> 4, o = tid & 15;
        float acc = b2[o];
        for (int k4 = 0; k4 < 64; ++k4) {
            const float4 av = *(const float4*)&B[r][4 * k4];
            acc = fmaf(av.x, w2t[(4 * k4 + 0) * 16 + o],
                  fmaf(av.y, w2t[(4 * k4 + 1) * 16 + o],
                  fmaf(av.z, w2t[(4 * k4 + 2) * 16 + o],
                  fmaf(av.w, w2t[(4 * k4 + 3) * 16 + o], acc))));
        }
        u_out[(n0 + r) * 16 + o] = acc * (1.f / N_NODES);
    }
}

// ---------------- p MLP: 256->128->256->256->16->256, avg dirs, /E ----------
// wave = row-group of 8 rows; thread = (rg, ct) with C output cols per thread.
__global__ __launch_bounds__(256, 3) void pmlp_kernel(
    const float* __restrict__ h, const int* __restrict__ edges,
    const float* __restrict__ w0t, const float* __restrict__ b0,
    const float* __restrict__ w1t, const float* __restrict__ b1,
    const float* __restrict__ w2t, const float* __restrict__ b2,
    const float* __restrict__ w3t, const float* __restrict__ b3,
    const float* __restrict__ w4t, const float* __restrict__ b4,
    float* __restrict__ p_out, float* __restrict__ pT)
{
    __shared__ float A[32][256];   // 32 KB
    __shared__ float B[32][128];   // 16 KB
    __shared__ float C16[32][16];  // 2 KB
    __shared__ int fi[32], se[32];
    const int tid = threadIdx.x;
    const int e0 = blockIdx.x * 16;
    const int rg = tid >> 6;       // wave id = row group
    const int ct = tid & 63;
    const int r0 = rg * 8;

    if (tid < 16) {
        int i = edges[2 * (e0 + tid)], j = edges[2 * (e0 + tid) + 1];
        fi[2 * tid] = i;     se[2 * tid] = j;       // row 2s  = [h_i | h_j]
        fi[2 * tid + 1] = j; se[2 * tid + 1] = i;   // row 2s+1 = [h_j | h_i]
    }
    __syncthreads();
    {
        int c = tid, cl = c & 127;
        for (int r = 0; r < 32; ++r) {
            int node = (c < 128) ? fi[r] : se[r];
            A[r][c] = h[node * 128 + cl];
        }
    }
    __syncthreads();
    // L0: 256->128 relu, A->B.  C=2 cols/thread (float2 weights), prefetched.
    {
        const float2* wp = (const float2*)w0t + ct;   // w0t[k*128 + 2ct]
        float2 cw[4], nw[4];
        #pragma unroll
        for (int c = 0; c < 4; ++c) cw[c] = wp[c * 64];
        float2 bb = ((const float2*)b0)[ct];
        float a0[8], a1[8];
        #pragma unroll
        for (int r = 0; r < 8; ++r) { a0[r] = bb.x; a1[r] = bb.y; }
        for (int k4 = 0; k4 < 64; ++k4) {
            if (k4 < 63) {
                #pragma unroll
                for (int c = 0; c < 4; ++c) nw[c] = wp[(4 * k4 + 4 + c) * 64];
            }
            #pragma unroll
            for (int r = 0; r < 8; ++r) {
                const float4 av = *(const float4*)&A[r0 + r][4 * k4];
                a0[r] = fmaf(av.x, cw[0].x, fmaf(av.y, cw[1].x, fmaf(av.z, cw[2].x, fmaf(av.w, cw[3].x, a0[r]))));
                a1[r] = fmaf(av.x, cw[0].y, fmaf(av.y, cw[1].y, fmaf(av.z, cw[2].y, fmaf(av.w, cw[3].y, a1[r]))));
            }
            #pragma unroll
            for (int c = 0; c < 4; ++c) cw[c] = nw[c];
        }
        #pragma unroll
        for (int r = 0; r < 8; ++r) {
            B[r0 + r][2 * ct]     = fmaxf(a0[r], 0.f);
            B[r0 + r][2 * ct + 1] = fmaxf(a1[r], 0.f);
        }
    }
    __syncthreads();
    // L1: 128->256 relu, B->A.  C=4 cols/thread (float4 weights), prefetched.
    {
        const float4* wp = (const float4*)w1t + ct;   // w1t[k*256 + 4ct]
        float4 cw[4], nw[4];
        #pragma unroll
        for (int c = 0; c < 4; ++c) cw[c] = wp[c * 64];
        float4 bb = ((const float4*)b1)[ct];
        float acc[8][4];
        #pragma unroll
        for (int r = 0; r < 8; ++r) {
            acc[r][0] = bb.x; acc[r][1] = bb.y; acc[r][2] = bb.z; acc[r][3] = bb.w;
        }
        for (int k4 = 0; k4 < 32; ++k4) {
            if (k4 < 31) {
                #pragma unroll
                for (int c = 0; c < 4; ++c) nw[c] = wp[(4 * k4 + 4 + c) * 64];
            }
            #pragma unroll
            for (int r = 0; r < 8; ++r) {
                const float4 av = *(const float4*)&B[r0 + r][4 * k4];
                acc[r][0] = fmaf(av.x, cw[0].x, fmaf(av.y, cw[1].x, fmaf(av.z, cw[2].x, fmaf(av.w, cw[3].x, acc[r][0]))));
                acc[r][1] = fmaf(av.x, cw[0].y, fmaf(av.y, cw[1].y, fmaf(av.z, cw[2].y, fmaf(av.w, cw[3].y, acc[r][1]))));
                acc[r][2] = fmaf(av.x, cw[0].z, fmaf(av.y, cw[1].z, fmaf(av.z, cw[2].z, fmaf(av.w, cw[3].z, acc[r][2]))));
                acc[r][3] = fmaf(av.x, cw[0].w, fmaf(av.y, cw[1].w, fmaf(av.z, cw[2].w, fmaf(av.w, cw[3].w, acc[r][3]))));
            }
            #pragma unroll
            for (int c = 0; c < 4; ++c) cw[c] = nw[c];
        }
        #pragma unroll
        for (int r = 0; r < 8; ++r) {
            float4 v = make_float4(fmaxf(acc[r][0], 0.f), fmaxf(acc[r][1], 0.f),
                                   fmaxf(acc[r][2], 0.f), fmaxf(acc[r][3], 0.f));
            *(float4*)&A[r0 + r][4 * ct] = v;
        }
    }
    __syncthreads();
    // L2: 256->256 relu, A->A (register staged).  C=4, prefetched.
    {
        const float4* wp = (const float4*)w2t + ct;
        float4 cw[4], nw[4];
        #pragma unroll
        for (int c = 0; c < 4; ++c) cw[c] = wp[c * 64];
        float4 bb = ((const float4*)b2)[ct];
        float acc[8][4];
        #pragma unroll
        for (int r = 0; r < 8; ++r) {
            acc[r][0] = bb.x; acc[r][1] = bb.y; acc[r][2] = bb.z; acc[r][3] = bb.w;
        }
        for (int k4 = 0; k4 < 64; ++k4) {
            if (k4 < 63) {
                #pragma unroll
                for (int c = 0; c < 4; ++c) nw[c] = wp[(4 * k4 + 4 + c) * 64];
            }
            #pragma unroll
            for (int r = 0; r < 8; ++r) {
                const float4 av = *(const float4*)&A[r0 + r][4 * k4];
                acc[r][0] = fmaf(av.x, cw[0].x, fmaf(av.y, cw[1].x, fmaf(av.z, cw[2].x, fmaf(av.w, cw[3].x, acc[r][0]))));
                acc[r][1] = fmaf(av.x, cw[0].y, fmaf(av.y, cw[1].y, fmaf(av.z, cw[2].y, fmaf(av.w, cw[3].y, acc[r][1]))));
                acc[r][2] = fmaf(av.x, cw[0].z, fmaf(av.y, cw[1].z, fmaf(av.z, cw[2].z, fmaf(av.w, cw[3].z, acc[r][2]))));
                acc[r][3] = fmaf(av.x, cw[0].w, fmaf(av.y, cw[1].w, fmaf(av.z, cw[2].w, fmaf(av.w, cw[3].w, acc[r][3]))));
            }
            #pragma unroll
            for (int c = 0; c < 4; ++c) cw[c] = nw[c];
        }
        __syncthreads();
        #pragma unroll
        for (int r = 0; r < 8; ++r) {
            float4 v = make_float4(fmaxf(acc[r][0], 0.f), fmaxf(acc[r][1], 0.f),
                                   fmaxf(acc[r][2], 0.f), fmaxf(acc[r][3], 0.f));
            *(float4*)&A[r0 + r][4 * ct] = v;
        }
    }
    __syncthreads();
    // L3: 256->16 relu, A->C16   (512 tasks)
    for (int idx = tid; idx < 512; idx += 256) {
        int r = idx >> 4, o = idx & 15;
        float acc = b3[o];
        for (int k4 = 0; k4 < 64; ++k4) {
            const float4 av = *(const float4*)&A[r][4 * k4];
            acc = fmaf(av.x, w3t[(4 * k4 + 0) * 16 + o],
                  fmaf(av.y, w3t[(4 * k4 + 1) * 16 + o],
                  fmaf(av.z, w3t[(4 * k4 + 2) * 16 + o],
                  fmaf(av.w, w3t[(4 * k4 + 3) * 16 + o], acc))));
        }
        C16[r][o] = fmaxf(acc, 0.f);
    }
    __syncthreads();
    // L4: 16->256 (no relu), combine dirs, /E ; write p and pT
    {
        int o = tid;
        int ai = o >> 4, aj = o & 15;
        float acc[32];
        #pragma unroll
        for (int r = 0; r < 32; ++r) acc[r] = b4[o];
        #pragma unroll
        for (int k4 = 0; k4 < 4; ++k4) {
            float w0v = w4t[(4 * k4 + 0) * 256 + o];
            float w1v = w4t[(4 * k4 + 1) * 256 + o];
            float w2v = w4t[(4 * k4 + 2) * 256 + o];
            float w3v = w4t[(4 * k4 + 3) * 256 + o];
            #pragma unroll
            for (int r = 0; r < 32; ++r) {
                const float4 av = *(const float4*)&C16[r][4 * k4];
                acc[r] = fmaf(av.x, w0v, fmaf(av.y, w1v, fmaf(av.z, w2v, fmaf(av.w, w3v, acc[r]))));
            }
        }
        #pragma unroll
        for (int s = 0; s < 16; ++s) {
            float v = 0.5f * (acc[2 * s] + acc[2 * s + 1]) * (1.f / NE);
            p_out[(e0 + s) * 256 + o] = v;
            pT[(e0 + s) * 256 + aj * 16 + ai] = v;   // pT[e][aj][ai]
        }
    }
}

// ---------------- merged MP iteration kernel --------------------------------
// blocks 0..999: edge phase for iter t (reads S[t], msg; writes S[t+1], msg).
// blocks 1000..1070: node phase for iter t-1 (reads S[t] — completed by the
// PREVIOUS launch; the stream boundary is the global sync). S[0] is all-zero.
__global__ __launch_bounds__(256) void mp_iter_kernel(
    const float* __restrict__ u, float* __restrict__ Sbuf,
    float* __restrict__ msg, const float* __restrict__ pT,
    const float* __restrict__ p, const int* __restrict__ edges,
    const int* __restrict__ wflag, int* __restrict__ aidx,
    float* __restrict__ q, int t)
{
    const int tid = threadIdx.x;
    if (blockIdx.x < 1000) {
        // ---- edge phase, iter t ----
        const int gid = blockIdx.x * 256 + tid;
        const int e = gid >> 4;
        const int L = gid & 15;
        const float* So = Sbuf + t * 32000;
        float* Sn = Sbuf + (t + 1) * 32000;
        const int i = edges[2 * e], j = edges[2 * e + 1];
        const float mold_ij = msg[(NE + e) * 16 + L];   // into i
        const float mold_ji = msg[e * 16 + L];          // into j
        const float bi = u[i * 16 + L] + So[i * 16 + L] - mold_ij;
        const float bj = u[j * 16 + L] + So[j * 16 + L] - mold_ji;
        const float4* pt = (const float4*)(pT + e * 256 + L * 16);  // pT[e][L][*] = p[e][*][L]
        const float4 q0 = pt[0], q1 = pt[1], q2 = pt[2], q3 = pt[3];
        float pv[16] = {q0.x, q0.y, q0.z, q0.w, q1.x, q1.y, q1.z, q1.w,
                        q2.x, q2.y, q2.z, q2.w, q3.x, q3.y, q3.z, q3.w};
        float mj = -INFINITY, vmax = -INFINITY;
        #pragma unroll
        for (int a = 0; a < 16; ++a) {
            float v = pv[a];
            float bia = __shfl(bi, a, 16);
            mj = fmaxf(mj, v + bia);
            vmax = fmaxf(vmax, v);
        }
        float mi = vmax + bj;
        float sj = mj, si = mi;
        #pragma unroll
        for (int off = 1; off < 16; off <<= 1) {
            sj += __shfl_xor(sj, off, 16);
            si += __shfl_xor(si, off, 16);
        }
        mj -= sj * (1.f / 16.f);
        mi -= si * (1.f / 16.f);
        msg[e * 16 + L] = mj;
        msg[(NE + e) * 16 + L] = mi;
        if (wflag[e]) {  // only the representative of a duplicate pair feeds S
            atomicAdd(&Sn[j * 16 + L], mj);
            atomicAdd(&Sn[i * 16 + L], mi);
        }
    } else if (t > 0) {
        // ---- node phase, iter t-1 (S[t] complete as of previous launch) ----
        const int r = (blockIdx.x - 1000) * 256 + tid;
        const float* Sn = Sbuf + t * 32000;
        float partial = 0.f;
        if (r < N_NODES) {
            int n = r;
            float bv = u[n * 16] + Sn[n * 16];
            int best = 0;
            #pragma unroll
            for (int a = 1; a < 16; ++a) {
                float v = u[n * 16 + a] + Sn[n * 16 + a];
                if (v > bv) { bv = v; best = a; }
            }
            aidx[(t - 1) * N_NODES + n] = best;
            partial = u[n * 16 + best];
        } else if (r < N_NODES + NE) {
            int ee = r - N_NODES;
            int ii = edges[2 * ee], jj = edges[2 * ee + 1];
            float bvi = u[ii * 16] + Sn[ii * 16]; int ai = 0;
            #pragma unroll
            for (int a = 1; a < 16; ++a) {
                float v = u[ii * 16 + a] + Sn[ii * 16 + a];
                if (v > bvi) { bvi = v; ai = a; }
            }
            float bvj = u[jj * 16] + Sn[jj * 16]; int aj = 0;
            #pragma unroll
            for (int a = 1; a < 16; ++a) {
                float v = u[jj * 16 + a] + Sn[jj * 16 + a];
                if (v > bvj) { bvj = v; aj = a; }
            }
            partial = p[ee * 256 + ai * 16 + aj];
        }
        #pragma unroll
        for (int off = 1; off < 64; off <<= 1) partial += __shfl_xor(partial, off, 64);
        if ((tid & 63) == 0) atomicAdd(&q[t - 1], partial);
    }
}

// ---------------- tail node phase for the last iteration (t = NITERS-1) -----
__global__ __launch_bounds__(256) void mp_tail_kernel(
    const float* __restrict__ u, const float* __restrict__ Sbuf,
    const float* __restrict__ p, const int* __restrict__ edges,
    int* __restrict__ aidx, float* __restrict__ q)
{
    const int tid = threadIdx.x;
    const int r = blockIdx.x * 256 + tid;
    const float* Sn = Sbuf + NITERS * 32000;
    float partial = 0.f;
    if (r < N_NODES) {
        int n = r;
        float bv = u[n * 16] + Sn[n * 16];
        int best = 0;
        #pragma unroll
        for (int a = 1; a < 16; ++a) {
            float v = u[n * 16 + a] + Sn[n * 16 + a];
            if (v > bv) { bv = v; best = a; }
        }
        aidx[(NITERS - 1) * N_NODES + n] = best;
        partial = u[n * 16 + best];
    } else if (r < N_NODES + NE) {
        int ee = r - N_NODES;
        int ii = edges[2 * ee], jj = edges[2 * ee + 1];
        float bvi = u[ii * 16] + Sn[ii * 16]; int ai = 0;
        #pragma unroll
        for (int a = 1; a < 16; ++a) {
            float v = u[ii * 16 + a] + Sn[ii * 16 + a];
            if (v > bvi) { bvi = v; ai = a; }
        }
        float bvj = u[jj * 16] + Sn[jj * 16]; int aj = 0;
        #pragma unroll
        for (int a = 1; a < 16; ++a) {
            float v = u[jj * 16 + a] + Sn[jj * 16 + a];
            if (v > bvj) { bvj = v; aj = a; }
        }
        partial = p[ee * 256 + ai * 16 + aj];
    }
    #pragma unroll
    for (int off = 1; off < 64; off <<= 1) partial += __shfl_xor(partial, off, 64);
    if ((tid & 63) == 0) atomicAdd(&q[NITERS - 1], partial);
}

// ---------------- final: running strict-> max over iters, one-hot a ---------
__global__ __launch_bounds__(256) void final_kernel(
    const float* __restrict__ q, const int* __restrict__ aidx,
    float* __restrict__ a_out, float* __restrict__ q_out)
{
    int id = blockIdx.x * 256 + threadIdx.x;
    float cur = 0.f; int best_t = -1;
    #pragma unroll
    for (int t = 0; t < NITERS; ++t) {
        float qv = q[t];
        if (qv > cur) { cur = qv; best_t = t; }
    }
    if (id < N_NODES * 16) {
        int n = id >> 4, c = id & 15;
        float val = 0.f;
        if (best_t >= 0 && aidx[best_t * N_NODES + n] == c) val = 1.f;
        a_out[id] = val;
        if (id == 0) q_out[0] = cur;
    }
}

extern "C" void kernel_launch(void* const* d_in, const int* in_sizes, int n_in,
                              void* d_out, int out_size, void* d_ws, size_t ws_size,
                              hipStream_t stream)
{
    (void)in_sizes; (void)n_in; (void)out_size; (void)ws_size;
    const float* x    = (const float*)d_in[0];
    const float* pa   = (const float*)d_in[1];
    const float* st   = (const float*)d_in[2];
    const int*   edges= (const int*)d_in[3];
    const float* gwih = (const float*)d_in[4];
    const float* gwhh = (const float*)d_in[5];
    const float* gbih = (const float*)d_in[6];
    const float* gbhh = (const float*)d_in[7];
    const float* uW0 = (const float*)d_in[8];  const float* ub0 = (const float*)d_in[9];
    const float* uW1 = (const float*)d_in[10]; const float* ub1 = (const float*)d_in[11];
    const float* uW2 = (const float*)d_in[12]; const float* ub2 = (const float*)d_in[13];
    const float* pW0 = (const float*)d_in[14]; const float* pb0 = (const float*)d_in[15];
    const float* pW1 = (const float*)d_in[16]; const float* pb1 = (const float*)d_in[17];
    const float* pW2 = (const float*)d_in[18]; const float* pb2 = (const float*)d_in[19];
    const float* pW3 = (const float*)d_in[20]; const float* pb3 = (const float*)d_in[21];
    const float* pW4 = (const float*)d_in[22]; const float* pb4 = (const float*)d_in[23];

    float* out   = (float*)d_out;
    float* a_out = out;                 // 32000
    float* q_out = out + 32000;         // 1
    float* u_out = out + 32001;         // 32000
    float* p_out = out + 64001;         // 4,096,000
    float* h_out = out + 4160001;       // 256,000 (state_out)

    float* ws   = (float*)d_ws;
    float* msg  = ws + WS_MSG;
    float* Sbuf = ws + WS_SBUF;
    float* q    = ws + WS_Q;
    int*   aidx = (int*)(ws + WS_AIDX);
    int*   wfl  = (int*)(ws + WS_W);
    float* pT   = ws + WS_PT;
    int*   owner= (int*)(ws + WS_PT);   // aliases pT; dead before pmlp runs

    setup_kernel<<<2048, 256, 0, stream>>>(ws, uW0, uW1, uW2, pW0, pW1, pW2, pW3, pW4,
                                           gwih, gwhh);
    claim_kernel<<<(NE + 255) / 256, 256, 0, stream>>>(edges, owner);
    resolve_kernel<<<(NE + 255) / 256, 256, 0, stream>>>(edges, owner, wfl);
    gru_kernel<<<N_NODES / 8, 256, 0, stream>>>(x, pa, st, ws + WS_GIT, ws + WS_GHT,
                                                gbih, gbhh, h_out);
    umlp_kernel<<<N_NODES / 16, 256, 0, stream>>>(h_out, ws + WS_UW0T, ub0,
                                                  ws + WS_UW1T, ub1, ws + WS_UW2T, ub2, u_out);
    pmlp_kernel<<<NE / 16, 256, 0, stream>>>(h_out, edges,
                                             ws + WS_PW0T, pb0, ws + WS_PW1T, pb1,
                                             ws + WS_PW2T, pb2, ws + WS_PW3T, pb3,
                                             ws + WS_PW4T, pb4, p_out, pT);
    for (int t = 0; t < NITERS; ++t) {
        mp_iter_kernel<<<1071, 256, 0, stream>>>(u_out, Sbuf, msg, pT, p_out,
                                                 edges, wfl, aidx, q, t);
    }
    mp_tail_kernel<<<71, 256, 0, stream>>>(u_out, Sbuf, p_out, edges, aidx, q);
    final_kernel<<<(N_NODES * 16) / 256, 256, 0, stream>>>(q, aidx, a_out, q_out);
}

// Round 5
// 381.132 us; speedup vs baseline: 3.7423x; 1.1636x over previous
//
#include <hip/hip_runtime.h>
#include <math.h>

#define N_NODES 2000
#define NA 16
#define NOBS 64
#define NH 128
#define NE 16000
#define NITERS 8

// ---------------- workspace layout (float offsets) ----------------
#define WS_MSG       0                       // 2E*16 = 512000 floats (single buffer)
#define WS_SBUF      512000                  // 9 x 32000 = 288000 (S[0] stays zero)
#define WS_Q         800000                  // 8
#define WS_ZERO_CNT  800008                  // everything above zeroed in setup
#define WS_AIDX      800016                  // int[8*2000] = 16000
#define WS_W         816016                  // int[16000]
#define WS_PT        832016                  // pT 4,096,000 floats; owner map (4,000,000 ints) aliases
#define WS_GIT       (WS_PT + 4000000)       // wihT 80x384 = 30720 (spare of PT region; dead after gru)
#define WS_GHT       (WS_GIT + 30720)        // whhT 128x384 = 49152 (end 4,911,888 < WS_WB)
#define WS_WB        4928016                 // transposed weights base
#define WS_UW0T      (WS_WB + 0)             // 128x256
#define WS_UW1T      (WS_WB + 32768)         // 256x256
#define WS_UW2T      (WS_WB + 98304)         // 256x16
#define WS_PW0T      (WS_WB + 102400)        // 256x128
#define WS_PW1T      (WS_WB + 135168)        // 128x256
#define WS_PW2T      (WS_WB + 167936)        // 256x256
#define WS_PW3T      (WS_WB + 233472)        // 256x16
#define WS_PW4T      (WS_WB + 237568)        // 16x256
// end: 5,169,680 floats (~20.7 MB)
// NOTE: weight ping-pong prefetch reads up to ~2K floats past each array's
// end — always lands in the NEXT array in this layout (benign, verified).

// ---------------- setup: zero state, transpose weights ----------------------
__global__ __launch_bounds__(256) void setup_kernel(
    float* __restrict__ ws,
    const float* __restrict__ uW0, const float* __restrict__ uW1,
    const float* __restrict__ uW2, const float* __restrict__ pW0,
    const float* __restrict__ pW1, const float* __restrict__ pW2,
    const float* __restrict__ pW3, const float* __restrict__ pW4,
    const float* __restrict__ gwih, const float* __restrict__ gwhh)
{
    const int total = WS_ZERO_CNT + 321536;
    for (int idx = blockIdx.x * 256 + threadIdx.x; idx < total;
         idx += gridDim.x * 256) {
        if (idx < WS_ZERO_CNT) {
            ws[idx] = 0.f;
        } else {
            int t = idx - WS_ZERO_CNT;
            const float* src; float* dst; int K, O;
            if      (t < 32768)              { src = uW0;  dst = ws + WS_UW0T; K = 128; O = 256; }
            else if (t < 98304)  { t -= 32768;  src = uW1;  dst = ws + WS_UW1T; K = 256; O = 256; }
            else if (t < 102400) { t -= 98304;  src = uW2;  dst = ws + WS_UW2T; K = 256; O = 16;  }
            else if (t < 135168) { t -= 102400; src = pW0;  dst = ws + WS_PW0T; K = 256; O = 128; }
            else if (t < 167936) { t -= 135168; src = pW1;  dst = ws + WS_PW1T; K = 128; O = 256; }
            else if (t < 233472) { t -= 167936; src = pW2;  dst = ws + WS_PW2T; K = 256; O = 256; }
            else if (t < 237568) { t -= 233472; src = pW3;  dst = ws + WS_PW3T; K = 256; O = 16;  }
            else if (t < 241664) { t -= 237568; src = pW4;  dst = ws + WS_PW4T; K = 16;  O = 256; }
            else if (t < 272384) { t -= 241664; src = gwih; dst = ws + WS_GIT;  K = 80;  O = 384; }
            else                 { t -= 272384; src = gwhh; dst = ws + WS_GHT;  K = 128; O = 384; }
            int k = t / O, o = t % O;
            dst[t] = src[o * K + k];
            (void)K;
        }
    }
}

// ---------------- dedup: init only touched owner slots, claim, resolve ------
__global__ __launch_bounds__(256) void init_owner_kernel(
    const int* __restrict__ edges, int* __restrict__ owner)
{
    int e = blockIdx.x * 256 + threadIdx.x;
    if (e < NE) {
        int i = edges[2 * e], j = edges[2 * e + 1];
        owner[i * N_NODES + j] = -1;
    }
}

__global__ __launch_bounds__(256) void claim_kernel(
    const int* __restrict__ edges, int* __restrict__ owner)
{
    int e = blockIdx.x * 256 + threadIdx.x;
    if (e < NE) {
        int i = edges[2 * e], j = edges[2 * e + 1];
        atomicMax(&owner[i * N_NODES + j], e);
    }
}

__global__ __launch_bounds__(256) void resolve_kernel(
    const int* __restrict__ edges, const int* __restrict__ owner,
    int* __restrict__ wflag)
{
    int e = blockIdx.x * 256 + threadIdx.x;
    if (e < NE) {
        int i = edges[2 * e], j = edges[2 * e + 1];
        wflag[e] = (owner[i * N_NODES + j] == e) ? 1 : 0;
    }
}

// ---------------- GRU encoder: h = GRUCell(concat(x,pa), state) -------------
// weights pre-transposed (wihT[k][g], whhT[k][g]); activations read as float4
// (4x fewer LDS-pipe instructions vs scalar broadcast reads).
__global__ __launch_bounds__(256) void gru_kernel(
    const float* __restrict__ x, const float* __restrict__ pa,
    const float* __restrict__ st, const float* __restrict__ wihT,
    const float* __restrict__ whhT, const float* __restrict__ bih,
    const float* __restrict__ bhh, float* __restrict__ h_out)
{
    __shared__ float enc[8][80];
    __shared__ float hp[8][128];
    __shared__ float gi[8][384];
    __shared__ float gh[8][384];
    const int tid = threadIdx.x;
    const int n0 = blockIdx.x * 8;

    for (int idx = tid; idx < 8 * 80; idx += 256) {
        int r = idx / 80, c = idx % 80;
        enc[r][c] = (c < 64) ? x[(n0 + r) * 64 + c] : pa[(n0 + r) * 16 + (c - 64)];
    }
    for (int idx = tid; idx < 8 * 128; idx += 256) {
        int r = idx >> 7, c = idx & 127;
        hp[r][c] = st[(n0 + r) * 128 + c];
    }
    __syncthreads();

    for (int idx = tid; idx < 8 * 384; idx += 256) {
        int g = idx % 384, r = idx / 384;
        float s1 = bih[g];
        #pragma unroll 5
        for (int k4 = 0; k4 < 20; ++k4) {
            const float4 ev = *(const float4*)&enc[r][4 * k4];
            s1 = fmaf(ev.x, wihT[(4 * k4 + 0) * 384 + g],
                 fmaf(ev.y, wihT[(4 * k4 + 1) * 384 + g],
                 fmaf(ev.z, wihT[(4 * k4 + 2) * 384 + g],
                 fmaf(ev.w, wihT[(4 * k4 + 3) * 384 + g], s1))));
        }
        gi[r][g] = s1;
        float s2 = bhh[g];
        #pragma unroll 8
        for (int k4 = 0; k4 < 32; ++k4) {
            const float4 hv = *(const float4*)&hp[r][4 * k4];
            s2 = fmaf(hv.x, whhT[(4 * k4 + 0) * 384 + g],
                 fmaf(hv.y, whhT[(4 * k4 + 1) * 384 + g],
                 fmaf(hv.z, whhT[(4 * k4 + 2) * 384 + g],
                 fmaf(hv.w, whhT[(4 * k4 + 3) * 384 + g], s2))));
        }
        gh[r][g] = s2;
    }
    __syncthreads();

    for (int idx = tid; idx < 8 * 128; idx += 256) {
        int r = idx >> 7, c = idx & 127;
        float rr = 1.f / (1.f + expf(-(gi[r][c] + gh[r][c])));
        float zz = 1.f / (1.f + expf(-(gi[r][128 + c] + gh[r][128 + c])));
        float nn = tanhf(gi[r][256 + c] + rr * gh[r][256 + c]);
        h_out[(n0 + r) * 128 + c] = (1.f - zz) * nn + zz * hp[r][c];
    }
}

// ---------------- u MLP: 128 -> 256 -> 256 -> 16, /N ----------------
// 8 rows/block (250 blocks -> all CUs busy), ping-pong weight prefetch.
__global__ __launch_bounds__(256) void umlp_kernel(
    const float* __restrict__ h, const float* __restrict__ w0t,
    const float* __restrict__ b0, const float* __restrict__ w1t,
    const float* __restrict__ b1, const float* __restrict__ w2t,
    const float* __restrict__ b2, float* __restrict__ u_out)
{
    __shared__ float A[8][128];
    __shared__ float B[8][256];
    const int tid = threadIdx.x;
    const int n0 = blockIdx.x * 8;

    for (int idx = tid; idx < 8 * 128; idx += 256) {
        int r = idx >> 7, c = idx & 127;
        A[r][c] = h[(n0 + r) * 128 + c];
    }
    __syncthreads();
    // L0: 128->256 relu, A->B
    {
        const int o = tid;
        const float* wp = w0t + o;
        float wA[4], wB[4];
        #pragma unroll
        for (int c = 0; c < 4; ++c) wA[c] = wp[c * 256];
        float acc[8];
        #pragma unroll
        for (int r = 0; r < 8; ++r) acc[r] = b0[o];
        for (int k4 = 0; k4 < 32; k4 += 2) {
            #pragma unroll
            for (int c = 0; c < 4; ++c) wB[c] = wp[(4 * (k4 + 1) + c) * 256];
            #pragma unroll
            for (int r = 0; r < 8; ++r) {
                const float4 av = *(const float4*)&A[r][4 * k4];
                acc[r] = fmaf(av.x, wA[0], fmaf(av.y, wA[1], fmaf(av.z, wA[2], fmaf(av.w, wA[3], acc[r]))));
            }
            #pragma unroll
            for (int c = 0; c < 4; ++c) wA[c] = wp[(4 * (k4 + 2) + c) * 256]; // benign OOB at last pair
            #pragma unroll
            for (int r = 0; r < 8; ++r) {
                const float4 av = *(const float4*)&A[r][4 * k4 + 4];
                acc[r] = fmaf(av.x, wB[0], fmaf(av.y, wB[1], fmaf(av.z, wB[2], fmaf(av.w, wB[3], acc[r]))));
            }
        }
        #pragma unroll
        for (int r = 0; r < 8; ++r) B[r][o] = fmaxf(acc[r], 0.f);
    }
    __syncthreads();
    // L1: 256->256 relu, B->B (register staged)
    {
        const int o = tid;
        const float* wp = w1t + o;
        float wA[4], wB[4];
        #pragma unroll
        for (int c = 0; c < 4; ++c) wA[c] = wp[c * 256];
        float acc[8];
        #pragma unroll
        for (int r = 0; r < 8; ++r) acc[r] = b1[o];
        for (int k4 = 0; k4 < 64; k4 += 2) {
            #pragma unroll
            for (int c = 0; c < 4; ++c) wB[c] = wp[(4 * (k4 + 1) + c) * 256];
            #pragma unroll
            for (int r = 0; r < 8; ++r) {
                const float4 av = *(const float4*)&B[r][4 * k4];
                acc[r] = fmaf(av.x, wA[0], fmaf(av.y, wA[1], fmaf(av.z, wA[2], fmaf(av.w, wA[3], acc[r]))));
            }
            #pragma unroll
            for (int c = 0; c < 4; ++c) wA[c] = wp[(4 * (k4 + 2) + c) * 256]; // benign OOB at last pair
            #pragma unroll
            for (int r = 0; r < 8; ++r) {
                const float4 av = *(const float4*)&B[r][4 * k4 + 4];
                acc[r] = fmaf(av.x, wB[0], fmaf(av.y, wB[1], fmaf(av.z, wB[2], fmaf(av.w, wB[3], acc[r]))));
            }
        }
        __syncthreads();
        #pragma unroll
        for (int r = 0; r < 8; ++r) B[r][o] = fmaxf(acc[r], 0.f);
    }
    __syncthreads();
    // L2: 256->16, /N, no relu (threads 0..127)
    if (tid < 128) {
        int r = tid >> 4, o = tid & 15;
        float acc = b2[o];
        for (int k4 = 0; k4 < 64; ++k4) {
            const float4 av = *(const float4*)&B[r][4 * k4];
            acc = fmaf(av.x, w2t[(4 * k4 + 0) * 16 + o],
                  fmaf(av.y, w2t[(4 * k4 + 1) * 16 + o],
                  fmaf(av.z, w2t[(4 * k4 + 2) * 16 + o],
                  fmaf(av.w, w2t[(4 * k4 + 3) * 16 + o], acc))));
        }
        u_out[(n0 + r) * 16 + o] = acc * (1.f / N_NODES);
    }
}

// ---------------- p MLP: 256->128->256->256->16->256, avg dirs, /E ----------
// wave = row-group of 8 rows; ping-pong weight regs (no rotate movs, no
// prefetch guard — OOB-by-one prefetch lands in the next ws array).
__global__ __launch_bounds__(256, 3) void pmlp_kernel(
    const float* __restrict__ h, const int* __restrict__ edges,
    const float* __restrict__ w0t, const float* __restrict__ b0,
    const float* __restrict__ w1t, const float* __restrict__ b1,
    const float* __restrict__ w2t, const float* __restrict__ b2,
    const float* __restrict__ w3t, const float* __restrict__ b3,
    const float* __restrict__ w4t, const float* __restrict__ b4,
    float* __restrict__ p_out, float* __restrict__ pT)
{
    __shared__ float A[32][256];   // 32 KB
    __shared__ float B[32][128];   // 16 KB
    __shared__ float C16[32][16];  // 2 KB
    __shared__ int fi[32], se[32];
    const int tid = threadIdx.x;
    const int e0 = blockIdx.x * 16;
    const int rg = tid >> 6;       // wave id = row group
    const int ct = tid & 63;
    const int r0 = rg * 8;

    if (tid < 16) {
        int i = edges[2 * (e0 + tid)], j = edges[2 * (e0 + tid) + 1];
        fi[2 * tid] = i;     se[2 * tid] = j;       // row 2s  = [h_i | h_j]
        fi[2 * tid + 1] = j; se[2 * tid + 1] = i;   // row 2s+1 = [h_j | h_i]
    }
    __syncthreads();
    {
        int c = tid, cl = c & 127;
        for (int r = 0; r < 32; ++r) {
            int node = (c < 128) ? fi[r] : se[r];
            A[r][c] = h[node * 128 + cl];
        }
    }
    __syncthreads();
    // L0: 256->128 relu, A->B.  2 cols/thread (float2 weights), ping-pong.
    {
        const float2* wp = (const float2*)w0t + ct;   // w0t[k*128 + 2ct]
        float2 wA[4], wB[4];
        #pragma unroll
        for (int c = 0; c < 4; ++c) wA[c] = wp[c * 64];
        float2 bb = ((const float2*)b0)[ct];
        float a0[8], a1[8];
        #pragma unroll
        for (int r = 0; r < 8; ++r) { a0[r] = bb.x; a1[r] = bb.y; }
        for (int k4 = 0; k4 < 64; k4 += 2) {
            #pragma unroll
            for (int c = 0; c < 4; ++c) wB[c] = wp[(4 * (k4 + 1) + c) * 64];
            #pragma unroll
            for (int r = 0; r < 8; ++r) {
                const float4 av = *(const float4*)&A[r0 + r][4 * k4];
                a0[r] = fmaf(av.x, wA[0].x, fmaf(av.y, wA[1].x, fmaf(av.z, wA[2].x, fmaf(av.w, wA[3].x, a0[r]))));
                a1[r] = fmaf(av.x, wA[0].y, fmaf(av.y, wA[1].y, fmaf(av.z, wA[2].y, fmaf(av.w, wA[3].y, a1[r]))));
            }
            #pragma unroll
            for (int c = 0; c < 4; ++c) wA[c] = wp[(4 * (k4 + 2) + c) * 64]; // benign OOB at last pair
            #pragma unroll
            for (int r = 0; r < 8; ++r) {
                const float4 av = *(const float4*)&A[r0 + r][4 * k4 + 4];
                a0[r] = fmaf(av.x, wB[0].x, fmaf(av.y, wB[1].x, fmaf(av.z, wB[2].x, fmaf(av.w, wB[3].x, a0[r]))));
                a1[r] = fmaf(av.x, wB[0].y, fmaf(av.y, wB[1].y, fmaf(av.z, wB[2].y, fmaf(av.w, wB[3].y, a1[r]))));
            }
        }
        #pragma unroll
        for (int r = 0; r < 8; ++r) {
            B[r0 + r][2 * ct]     = fmaxf(a0[r], 0.f);
            B[r0 + r][2 * ct + 1] = fmaxf(a1[r], 0.f);
        }
    }
    __syncthreads();
    // L1: 128->256 relu, B->A.  4 cols/thread (float4 weights), ping-pong.
    {
        const float4* wp = (const float4*)w1t + ct;   // w1t[k*256 + 4ct]
        float4 wA[4], wB[4];
        #pragma unroll
        for (int c = 0; c < 4; ++c) wA[c] = wp[c * 64];
        float4 bb = ((const float4*)b1)[ct];
        float acc[8][4];
        #pragma unroll
        for (int r = 0; r < 8; ++r) {
            acc[r][0] = bb.x; acc[r][1] = bb.y; acc[r][2] = bb.z; acc[r][3] = bb.w;
        }
        for (int k4 = 0; k4 < 32; k4 += 2) {
            #pragma unroll
            for (int c = 0; c < 4; ++c) wB[c] = wp[(4 * (k4 + 1) + c) * 64];
            #pragma unroll
            for (int r = 0; r < 8; ++r) {
                const float4 av = *(const float4*)&B[r0 + r][4 * k4];
                acc[r][0] = fmaf(av.x, wA[0].x, fmaf(av.y, wA[1].x, fmaf(av.z, wA[2].x, fmaf(av.w, wA[3].x, acc[r][0]))));
                acc[r][1] = fmaf(av.x, wA[0].y, fmaf(av.y, wA[1].y, fmaf(av.z, wA[2].y, fmaf(av.w, wA[3].y, acc[r][1]))));
                acc[r][2] = fmaf(av.x, wA[0].z, fmaf(av.y, wA[1].z, fmaf(av.z, wA[2].z, fmaf(av.w, wA[3].z, acc[r][2]))));
                acc[r][3] = fmaf(av.x, wA[0].w, fmaf(av.y, wA[1].w, fmaf(av.z, wA[2].w, fmaf(av.w, wA[3].w, acc[r][3]))));
            }
            #pragma unroll
            for (int c = 0; c < 4; ++c) wA[c] = wp[(4 * (k4 + 2) + c) * 64]; // benign OOB at last pair
            #pragma unroll
            for (int r = 0; r < 8; ++r) {
                const float4 av = *(const float4*)&B[r0 + r][4 * k4 + 4];
                acc[r][0] = fmaf(av.x, wB[0].x, fmaf(av.y, wB[1].x, fmaf(av.z, wB[2].x, fmaf(av.w, wB[3].x, acc[r][0]))));
                acc[r][1] = fmaf(av.x, wB[0].y, fmaf(av.y, wB[1].y, fmaf(av.z, wB[2].y, fmaf(av.w, wB[3].y, acc[r][1]))));
                acc[r][2] = fmaf(av.x, wB[0].z, fmaf(av.y, wB[1].z, fmaf(av.z, wB[2].z, fmaf(av.w, wB[3].z, acc[r][2]))));
                acc[r][3] = fmaf(av.x, wB[0].w, fmaf(av.y, wB[1].w, fmaf(av.z, wB[2].w, fmaf(av.w, wB[3].w, acc[r][3]))));
            }
        }
        #pragma unroll
        for (int r = 0; r < 8; ++r) {
            float4 v = make_float4(fmaxf(acc[r][0], 0.f), fmaxf(acc[r][1], 0.f),
                                   fmaxf(acc[r][2], 0.f), fmaxf(acc[r][3], 0.f));
            *(float4*)&A[r0 + r][4 * ct] = v;
        }
    }
    __syncthreads();
    // L2: 256->256 relu, A->A (register staged).  4 cols/thread, ping-pong.
    {
        const float4* wp = (const float4*)w2t + ct;
        float4 wA[4], wB[4];
        #pragma unroll
        for (int c = 0; c < 4; ++c) wA[c] = wp[c * 64];
        float4 bb = ((const float4*)b2)[ct];
        float acc[8][4];
        #pragma unroll
        for (int r = 0; r < 8; ++r) {
            acc[r][0] = bb.x; acc[r][1] = bb.y; acc[r][2] = bb.z; acc[r][3] = bb.w;
        }
        for (int k4 = 0; k4 < 64; k4 += 2) {
            #pragma unroll
            for (int c = 0; c < 4; ++c) wB[c] = wp[(4 * (k4 + 1) + c) * 64];
            #pragma unroll
            for (int r = 0; r < 8; ++r) {
                const float4 av = *(const float4*)&A[r0 + r][4 * k4];
                acc[r][0] = fmaf(av.x, wA[0].x, fmaf(av.y, wA[1].x, fmaf(av.z, wA[2].x, fmaf(av.w, wA[3].x, acc[r][0]))));
                acc[r][1] = fmaf(av.x, wA[0].y, fmaf(av.y, wA[1].y, fmaf(av.z, wA[2].y, fmaf(av.w, wA[3].y, acc[r][1]))));
                acc[r][2] = fmaf(av.x, wA[0].z, fmaf(av.y, wA[1].z, fmaf(av.z, wA[2].z, fmaf(av.w, wA[3].z, acc[r][2]))));
                acc[r][3] = fmaf(av.x, wA[0].w, fmaf(av.y, wA[1].w, fmaf(av.z, wA[2].w, fmaf(av.w, wA[3].w, acc[r][3]))));
            }
            #pragma unroll
            for (int c = 0; c < 4; ++c) wA[c] = wp[(4 * (k4 + 2) + c) * 64]; // benign OOB at last pair
            #pragma unroll
            for (int r = 0; r < 8; ++r) {
                const float4 av = *(const float4*)&A[r0 + r][4 * k4 + 4];
                acc[r][0] = fmaf(av.x, wB[0].x, fmaf(av.y, wB[1].x, fmaf(av.z, wB[2].x, fmaf(av.w, wB[3].x, acc[r][0]))));
                acc[r][1] = fmaf(av.x, wB[0].y, fmaf(av.y, wB[1].y, fmaf(av.z, wB[2].y, fmaf(av.w, wB[3].y, acc[r][1]))));
                acc[r][2] = fmaf(av.x, wB[0].z, fmaf(av.y, wB[1].z, fmaf(av.z, wB[2].z, fmaf(av.w, wB[3].z, acc[r][2]))));
                acc[r][3] = fmaf(av.x, wB[0].w, fmaf(av.y, wB[1].w, fmaf(av.z, wB[2].w, fmaf(av.w, wB[3].w, acc[r][3]))));
            }
        }
        __syncthreads();
        #pragma unroll
        for (int r = 0; r < 8; ++r) {
            float4 v = make_float4(fmaxf(acc[r][0], 0.f), fmaxf(acc[r][1], 0.f),
                                   fmaxf(acc[r][2], 0.f), fmaxf(acc[r][3], 0.f));
            *(float4*)&A[r0 + r][4 * ct] = v;
        }
    }
    __syncthreads();
    // L3: 256->16 relu, A->C16   (512 tasks)
    for (int idx = tid; idx < 512; idx += 256) {
        int r = idx >> 4, o = idx & 15;
        float acc = b3[o];
        for (int k4 = 0; k4 < 64; ++k4) {
            const float4 av = *(const float4*)&A[r][4 * k4];
            acc = fmaf(av.x, w3t[(4 * k4 + 0) * 16 + o],
                  fmaf(av.y, w3t[(4 * k4 + 1) * 16 + o],
                  fmaf(av.z, w3t[(4 * k4 + 2) * 16 + o],
                  fmaf(av.w, w3t[(4 * k4 + 3) * 16 + o], acc))));
        }
        C16[r][o] = fmaxf(acc, 0.f);
    }
    __syncthreads();
    // L4: 16->256 (no relu), combine dirs, /E ; write p and pT
    {
        int o = tid;
        int ai = o >> 4, aj = o & 15;
        float acc[32];
        #pragma unroll
        for (int r = 0; r < 32; ++r) acc[r] = b4[o];
        #pragma unroll
        for (int k4 = 0; k4 < 4; ++k4) {
            float w0v = w4t[(4 * k4 + 0) * 256 + o];
            float w1v = w4t[(4 * k4 + 1) * 256 + o];
            float w2v = w4t[(4 * k4 + 2) * 256 + o];
            float w3v = w4t[(4 * k4 + 3) * 256 + o];
            #pragma unroll
            for (int r = 0; r < 32; ++r) {
                const float4 av = *(const float4*)&C16[r][4 * k4];
                acc[r] = fmaf(av.x, w0v, fmaf(av.y, w1v, fmaf(av.z, w2v, fmaf(av.w, w3v, acc[r]))));
            }
        }
        #pragma unroll
        for (int s = 0; s < 16; ++s) {
            float v = 0.5f * (acc[2 * s] + acc[2 * s + 1]) * (1.f / NE);
            p_out[(e0 + s) * 256 + o] = v;
            pT[(e0 + s) * 256 + aj * 16 + ai] = v;   // pT[e][aj][ai]
        }
    }
}

// ---------------- merged MP iteration kernel --------------------------------
// blocks 0..999: edge phase for iter t (reads S[t], msg; writes S[t+1], msg).
// blocks 1000..1070: node phase for iter t-1 (reads S[t] — completed by the
// PREVIOUS launch; the stream boundary is the global sync). S[0] is all-zero.
__global__ __launch_bounds__(256) void mp_iter_kernel(
    const float* __restrict__ u, float* __restrict__ Sbuf,
    float* __restrict__ msg, const float* __restrict__ pT,
    const float* __restrict__ p, const int* __restrict__ edges,
    const int* __restrict__ wflag, int* __restrict__ aidx,
    float* __restrict__ q, int t)
{
    const int tid = threadIdx.x;
    if (blockIdx.x < 1000) {
        // ---- edge phase, iter t ----
        const int gid = blockIdx.x * 256 + tid;
        const int e = gid >> 4;
        const int L = gid & 15;
        const float* So = Sbuf + t * 32000;
        float* Sn = Sbuf + (t + 1) * 32000;
        const int i = edges[2 * e], j = edges[2 * e + 1];
        const float mold_ij = msg[(NE + e) * 16 + L];   // into i
        const float mold_ji = msg[e * 16 + L];          // into j
        const float bi = u[i * 16 + L] + So[i * 16 + L] - mold_ij;
        const float bj = u[j * 16 + L] + So[j * 16 + L] - mold_ji;
        const float4* pt = (const float4*)(pT + e * 256 + L * 16);  // pT[e][L][*] = p[e][*][L]
        const float4 q0 = pt[0], q1 = pt[1], q2 = pt[2], q3 = pt[3];
        float pv[16] = {q0.x, q0.y, q0.z, q0.w, q1.x, q1.y, q1.z, q1.w,
                        q2.x, q2.y, q2.z, q2.w, q3.x, q3.y, q3.z, q3.w};
        float mj = -INFINITY, vmax = -INFINITY;
        #pragma unroll
        for (int a = 0; a < 16; ++a) {
            float v = pv[a];
            float bia = __shfl(bi, a, 16);
            mj = fmaxf(mj, v + bia);
            vmax = fmaxf(vmax, v);
        }
        float mi = vmax + bj;
        float sj = mj, si = mi;
        #pragma unroll
        for (int off = 1; off < 16; off <<= 1) {
            sj += __shfl_xor(sj, off, 16);
            si += __shfl_xor(si, off, 16);
        }
        mj -= sj * (1.f / 16.f);
        mi -= si * (1.f / 16.f);
        msg[e * 16 + L] = mj;
        msg[(NE + e) * 16 + L] = mi;
        if (wflag[e]) {  // only the representative of a duplicate pair feeds S
            atomicAdd(&Sn[j * 16 + L], mj);
            atomicAdd(&Sn[i * 16 + L], mi);
        }
    } else if (t > 0) {
        // ---- node phase, iter t-1 (S[t] complete as of previous launch) ----
        const int r = (blockIdx.x - 1000) * 256 + tid;
        const float* Sn = Sbuf + t * 32000;
        float partial = 0.f;
        if (r < N_NODES) {
            int n = r;
            float bv = u[n * 16] + Sn[n * 16];
            int best = 0;
            #pragma unroll
            for (int a = 1; a < 16; ++a) {
                float v = u[n * 16 + a] + Sn[n * 16 + a];
                if (v > bv) { bv = v; best = a; }
            }
            aidx[(t - 1) * N_NODES + n] = best;
            partial = u[n * 16 + best];
        } else if (r < N_NODES + NE) {
            int ee = r - N_NODES;
            int ii = edges[2 * ee], jj = edges[2 * ee + 1];
            float bvi = u[ii * 16] + Sn[ii * 16]; int ai = 0;
            #pragma unroll
            for (int a = 1; a < 16; ++a) {
                float v = u[ii * 16 + a] + Sn[ii * 16 + a];
                if (v > bvi) { bvi = v; ai = a; }
            }
            float bvj = u[jj * 16] + Sn[jj * 16]; int aj = 0;
            #pragma unroll
            for (int a = 1; a < 16; ++a) {
                float v = u[jj * 16 + a] + Sn[jj * 16 + a];
                if (v > bvj) { bvj = v; aj = a; }
            }
            partial = p[ee * 256 + ai * 16 + aj];
        }
        #pragma unroll
        for (int off = 1; off < 64; off <<= 1) partial += __shfl_xor(partial, off, 64);
        if ((tid & 63) == 0) atomicAdd(&q[t - 1], partial);
    }
}

// ---------------- tail node phase for the last iteration (t = NITERS-1) -----
__global__ __launch_bounds__(256) void mp_tail_kernel(
    const float* __restrict__ u, const float* __restrict__ Sbuf,
    const float* __restrict__ p, const int* __restrict__ edges,
    int* __restrict__ aidx, float* __restrict__ q)
{
    const int tid = threadIdx.x;
    const int r = blockIdx.x * 256 + tid;
    const float* Sn = Sbuf + NITERS * 32000;
    float partial = 0.f;
    if (r < N_NODES) {
        int n = r;
        float bv = u[n * 16] + Sn[n * 16];
        int best = 0;
        #pragma unroll
        for (int a = 1; a < 16; ++a) {
            float v = u[n * 16 + a] + Sn[n * 16 + a];
            if (v > bv) { bv = v; best = a; }
        }
        aidx[(NITERS - 1) * N_NODES + n] = best;
        partial = u[n * 16 + best];
    } else if (r < N_NODES + NE) {
        int ee = r - N_NODES;
        int ii = edges[2 * ee], jj = edges[2 * ee + 1];
        float bvi = u[ii * 16] + Sn[ii * 16]; int ai = 0;
        #pragma unroll
        for (int a = 1; a < 16; ++a) {
            float v = u[ii * 16 + a] + Sn[ii * 16 + a];
            if (v > bvi) { bvi = v; ai = a; }
        }
        float bvj = u[jj * 16] + Sn[jj * 16]; int aj = 0;
        #pragma unroll
        for (int a = 1; a < 16; ++a) {
            float v = u[jj * 16 + a] + Sn[jj * 16 + a];
            if (v > bvj) { bvj = v; aj = a; }
        }
        partial = p[ee * 256 + ai * 16 + aj];
    }
    #pragma unroll
    for (int off = 1; off < 64; off <<= 1) partial += __shfl_xor(partial, off, 64);
    if ((tid & 63) == 0) atomicAdd(&q[NITERS - 1], partial);
}

// ---------------- final: running strict-> max over iters, one-hot a ---------
__global__ __launch_bounds__(256) void final_kernel(
    const float* __restrict__ q, const int* __restrict__ aidx,
    float* __restrict__ a_out, float* __restrict__ q_out)
{
    int id = blockIdx.x * 256 + threadIdx.x;
    float cur = 0.f; int best_t = -1;
    #pragma unroll
    for (int t = 0; t < NITERS; ++t) {
        float qv = q[t];
        if (qv > cur) { cur = qv; best_t = t; }
    }
    if (id < N_NODES * 16) {
        int n = id >> 4, c = id & 15;
        float val = 0.f;
        if (best_t >= 0 && aidx[best_t * N_NODES + n] == c) val = 1.f;
        a_out[id] = val;
        if (id == 0) q_out[0] = cur;
    }
}

extern "C" void kernel_launch(void* const* d_in, const int* in_sizes, int n_in,
                              void* d_out, int out_size, void* d_ws, size_t ws_size,
                              hipStream_t stream)
{
    (void)in_sizes; (void)n_in; (void)out_size; (void)ws_size;
    const float* x    = (const float*)d_in[0];
    const float* pa   = (const float*)d_in[1];
    const float* st   = (const float*)d_in[2];
    const int*   edges= (const int*)d_in[3];
    const float* gwih = (const float*)d_in[4];
    const float* gwhh = (const float*)d_in[5];
    const float* gbih = (const float*)d_in[6];
    const float* gbhh = (const float*)d_in[7];
    const float* uW0 = (const float*)d_in[8];  const float* ub0 = (const float*)d_in[9];
    const float* uW1 = (const float*)d_in[10]; const float* ub1 = (const float*)d_in[11];
    const float* uW2 = (const float*)d_in[12]; const float* ub2 = (const float*)d_in[13];
    const float* pW0 = (const float*)d_in[14]; const float* pb0 = (const float*)d_in[15];
    const float* pW1 = (const float*)d_in[16]; const float* pb1 = (const float*)d_in[17];
    const float* pW2 = (const float*)d_in[18]; const float* pb2 = (const float*)d_in[19];
    const float* pW3 = (const float*)d_in[20]; const float* pb3 = (const float*)d_in[21];
    const float* pW4 = (const float*)d_in[22]; const float* pb4 = (const float*)d_in[23];

    float* out   = (float*)d_out;
    float* a_out = out;                 // 32000
    float* q_out = out + 32000;         // 1
    float* u_out = out + 32001;         // 32000
    float* p_out = out + 64001;         // 4,096,000
    float* h_out = out + 4160001;       // 256,000 (state_out)

    float* ws   = (float*)d_ws;
    float* msg  = ws + WS_MSG;
    float* Sbuf = ws + WS_SBUF;
    float* q    = ws + WS_Q;
    int*   aidx = (int*)(ws + WS_AIDX);
    int*   wfl  = (int*)(ws + WS_W);
    float* pT   = ws + WS_PT;
    int*   owner= (int*)(ws + WS_PT);   // aliases pT; dead before pmlp runs

    setup_kernel<<<1024, 256, 0, stream>>>(ws, uW0, uW1, uW2, pW0, pW1, pW2, pW3, pW4,
                                           gwih, gwhh);
    init_owner_kernel<<<(NE + 255) / 256, 256, 0, stream>>>(edges, owner);
    claim_kernel<<<(NE + 255) / 256, 256, 0, stream>>>(edges, owner);
    resolve_kernel<<<(NE + 255) / 256, 256, 0, stream>>>(edges, owner, wfl);
    gru_kernel<<<N_NODES / 8, 256, 0, stream>>>(x, pa, st, ws + WS_GIT, ws + WS_GHT,
                                                gbih, gbhh, h_out);
    umlp_kernel<<<N_NODES / 8, 256, 0, stream>>>(h_out, ws + WS_UW0T, ub0,
                                                 ws + WS_UW1T, ub1, ws + WS_UW2T, ub2, u_out);
    pmlp_kernel<<<NE / 16, 256, 0, stream>>>(h_out, edges,
                                             ws + WS_PW0T, pb0, ws + WS_PW1T, pb1,
                                             ws + WS_PW2T, pb2, ws + WS_PW3T, pb3,
                                             ws + WS_PW4T, pb4, p_out, pT);
    for (int t = 0; t < NITERS; ++t) {
        mp_iter_kernel<<<1071, 256, 0, stream>>>(u_out, Sbuf, msg, pT, p_out,
                                                 edges, wfl, aidx, q, t);
    }
    mp_tail_kernel<<<71, 256, 0, stream>>>(u_out, Sbuf, p_out, edges, aidx, q);
    final_kernel<<<(N_NODES * 16) / 256, 256, 0, stream>>>(q, aidx, a_out, q_out);
}